// Round 10
// baseline (130.489 us; speedup 1.0000x reference)
//
#include <hip/hip_runtime.h>
#include <stdint.h>

#define NNODE 1000
#define KSP   200
#define DIM   64
#define BATCH 8
#define NPAIR 4                         // producer/consumer pairs per block
#define NPP   2                         // nodes per pair
#define NPB   (NPAIR * NPP)             // 8 nodes per block
#define NBLK  (BATCH * NNODE / NPB)     // 1000 blocks

__global__ __launch_bounds__(512) void knn_pc_kernel(
    const float* __restrict__ locs,   // [B, N, 2]
    const float* __restrict__ emb,    // [B, N, 64]
    const float* __restrict__ W,      // [64]
    const float* __restrict__ bias,   // [64]
    float* __restrict__ out)
{
    __shared__ int      hist[NPAIR][256];          // 4 KB
    __shared__ uint64_t cand[NPAIR][256];          // 8 KB
    __shared__ float    ring[NPAIR][NPP][2][KSP];  // 12.8 KB: [pair][buf][d|nbr][200]
    __shared__ int      prodSeq[NPAIR];
    __shared__ int      ssp[NPAIR];

    const int tid  = threadIdx.x;
    const int wv   = tid >> 6;
    const int lane = tid & 63;
    const bool producer = (wv < NPAIR);
    const int p = producer ? wv : wv - NPAIR;

    if (tid < NPAIR) prodSeq[tid] = 0;
    __syncthreads();                               // flags visible to all waves

    const size_t E = (size_t)BATCH * NNODE * KSP;
    float* x_out = out;
    float* ei0   = out + (size_t)BATCH * NNODE * DIM;
    float* ei1   = ei0 + E;
    float* eemb  = ei1 + E;

    if (producer) {
        for (int m = 0; m < NPP; ++m) {
            const int node = blockIdx.x * NPB + p * NPP + m;
            const int b    = node / NNODE;
            const int i    = node - b * NNODE;

            #pragma unroll
            for (int c = 0; c < 4; ++c) hist[p][c * 64 + lane] = 0;
            if (lane == 0) ssp[p] = KSP + 1;
            __builtin_amdgcn_wave_barrier();

            const float2* loc = (const float2*)(locs + (size_t)b * NNODE * 2);
            const float2 self = loc[i];

            // pass 1: distances (exact XLA rounding) + histogram
            for (int j = lane; j < NNODE; j += 64) {
                float2 pt = loc[j];
                float dx = __fsub_rn(self.x, pt.x);
                float dy = __fsub_rn(self.y, pt.y);
                float d  = __fsqrt_rn(__fadd_rn(__fmul_rn(dx, dx), __fmul_rn(dy, dy)));
                int q = (int)(d * 180.0f);
                q = q > 255 ? 255 : q;
                atomicAdd(&hist[p][q], 1);
            }
            __builtin_amdgcn_wave_barrier();

            // scan: pick bin B (cum >= 201); hist <- exclusive bin starts
            int base = 0, Bcand = 1 << 30;
            #pragma unroll
            for (int c = 0; c < 4; ++c) {
                int x  = hist[p][c * 64 + lane];
                int sc = x;
                #pragma unroll
                for (int off = 1; off < 64; off <<= 1) {
                    int y = __shfl_up(sc, off, 64);
                    if (lane >= off) sc += y;
                }
                int cum = sc + base;
                if (cum >= KSP + 1 && Bcand == (1 << 30)) Bcand = c * 64 + lane;
                hist[p][c * 64 + lane] = cum - x;
                base += __shfl(sc, 63, 64);
            }
            #pragma unroll
            for (int off = 32; off; off >>= 1) Bcand = min(Bcand, __shfl_xor(Bcand, off, 64));
            const int B = Bcand;
            __builtin_amdgcn_wave_barrier();

            // pass 2: counting-sort placement
            for (int j = lane; j < NNODE; j += 64) {
                float2 pt = loc[j];
                float dx = __fsub_rn(self.x, pt.x);
                float dy = __fsub_rn(self.y, pt.y);
                float d  = __fsqrt_rn(__fadd_rn(__fmul_rn(dx, dx), __fmul_rn(dy, dy)));
                int q = (int)(d * 180.0f);
                q = q > 255 ? 255 : q;
                if (q <= B) {
                    int slot = atomicAdd(&hist[p][q], 1);
                    if (slot < 256)
                        cand[p][slot] = ((uint64_t)__float_as_uint(d) << 32) | (uint32_t)j;
                }
            }
            __builtin_amdgcn_wave_barrier();

            const int cumB = min(hist[p][B], 256);

            // exact rank: bin start + smaller-in-bin count
            uint64_t mykey[4];
            int      myrank[4];
            #pragma unroll
            for (int s = 0; s < 4; ++s) {
                int t = lane + s * 64;
                myrank[s] = KSP + 1;
                if (t < cumB) {
                    uint64_t k = cand[p][t];
                    float d = __uint_as_float((uint32_t)(k >> 32));
                    int q = (int)(d * 180.0f);
                    q = q > 255 ? 255 : q;
                    int start = q ? hist[p][q - 1] : 0;
                    int end   = min(hist[p][q], 256);
                    int r = start;
                    for (int mm = start; mm < end; ++mm)
                        r += (cand[p][mm] < k) ? 1 : 0;
                    mykey[s]  = k;
                    myrank[s] = r;
                }
            }
            // locate self (exactly one lane/slot matches)
            #pragma unroll
            for (int s = 0; s < 4; ++s) {
                int t = lane + s * 64;
                if (t < cumB && (uint32_t)mykey[s] == (uint32_t)i) ssp[p] = myrank[s];
            }
            __builtin_amdgcn_wave_barrier();
            const int sp = ssp[p];

            // emit sorted (d, nbr) into ring buffer m, self removed
            #pragma unroll
            for (int s = 0; s < 4; ++s) {
                int t = lane + s * 64;
                if (t < cumB) {
                    int r = myrank[s];
                    if (r <= KSP && r != sp) {
                        int tt = r - (r > sp ? 1 : 0);
                        ring[p][m][0][tt] = __uint_as_float((uint32_t)(mykey[s] >> 32));
                        ring[p][m][1][tt] = (float)(b * NNODE + (int)(uint32_t)mykey[s]);
                    }
                }
            }
            __threadfence_block();
            if (lane == 0)
                __hip_atomic_store(&prodSeq[p], m + 1, __ATOMIC_RELEASE,
                                   __HIP_MEMORY_SCOPE_WORKGROUP);
            __builtin_amdgcn_wave_barrier();
        }
    } else {
        // per-lane W/bias registers (channel group invariant)
        const int c4 = (lane & 15) << 2;
        const float4 w4 = *(const float4*)(W + c4);
        const float4 b4 = *(const float4*)(bias + c4);

        // independent stores first: x rows + ei0 for both nodes
        #pragma unroll
        for (int m = 0; m < NPP; ++m) {
            const int node = blockIdx.x * NPB + p * NPP + m;
            x_out[(size_t)node * DIM + lane] = emb[(size_t)node * DIM + lane];
            const size_t ebase = (size_t)node * KSP;
            for (int t = lane; t < KSP; t += 64) ei0[ebase + t] = (float)node;
        }

        for (int m = 0; m < NPP; ++m) {
            const int node = blockIdx.x * NPB + p * NPP + m;
            const size_t ebase = (size_t)node * KSP;

            while (__hip_atomic_load(&prodSeq[p], __ATOMIC_ACQUIRE,
                                     __HIP_MEMORY_SCOPE_WORKGROUP) <= m)
                __builtin_amdgcn_s_sleep(8);

            // ei1 from ring
            for (int t = lane; t < KSP; t += 64)
                ei1[ebase + t] = ring[p][m][1][t];

            // eemb: 200 edges x 16 float4, coalesced
            float4* em4 = (float4*)(eemb + ebase * DIM);
            for (int t = lane; t < KSP * (DIM / 4); t += 64) {
                int e = t >> 4;
                float d = ring[p][m][0][e];
                float4 v;
                v.x = fmaf(d, w4.x, b4.x);
                v.y = fmaf(d, w4.y, b4.y);
                v.z = fmaf(d, w4.z, b4.z);
                v.w = fmaf(d, w4.w, b4.w);
                em4[t] = v;
            }
        }
    }
}

extern "C" void kernel_launch(void* const* d_in, const int* in_sizes, int n_in,
                              void* d_out, int out_size, void* d_ws, size_t ws_size,
                              hipStream_t stream) {
    const float* locs = (const float*)d_in[0];
    const float* emb  = (const float*)d_in[1];
    const float* W    = (const float*)d_in[2];
    const float* bias = (const float*)d_in[3];
    float* out = (float*)d_out;

    knn_pc_kernel<<<NBLK, 512, 0, stream>>>(locs, emb, W, bias, out);
}

// Round 12
// 93.380 us; speedup vs baseline: 1.3974x; 1.3974x over previous
//
#include <hip/hip_runtime.h>
#include <stdint.h>

#define NNODE 1000
#define KSP   200
#define DIM   64
#define BATCH 8
#define WPB   8                          // waves (nodes) per block, 512 threads
#define NBLK  (BATCH * NNODE / WPB)      // 1000 blocks

__global__ __launch_bounds__(512) void knn_edge_kernel(
    const float* __restrict__ locs,   // [B, N, 2]
    const float* __restrict__ emb,    // [B, N, 64]
    const float* __restrict__ W,      // [64]
    const float* __restrict__ bias,   // [64]
    float* __restrict__ out)
{
    __shared__ float4   sloc4[NNODE / 2];    // 1000 float2 = 500 float4 = 8 KB
    __shared__ int      hist[WPB][256];      // 8 KB
    __shared__ uint64_t cand[WPB][256];      // 16 KB
    __shared__ int      ssp[WPB];

    const int tid  = threadIdx.x;
    const int w    = tid >> 6;
    const int lane = tid & 63;
    const int node = blockIdx.x * WPB + w;   // 0 .. 7999
    const int b    = node / NNODE;           // uniform across block (8 | 1000)
    const int i    = node - b * NNODE;

    // ---- stage batch locs to LDS (500 float4, one per thread tid<500) ----
    if (tid < NNODE / 2) sloc4[tid] = ((const float4*)(locs + (size_t)b * NNODE * 2))[tid];
    ((int4*)hist)[tid] = make_int4(0, 0, 0, 0);        // 512 * int4 = 2048 ints exact
    if (tid < WPB) ssp[tid] = KSP + 1;
    __syncthreads();                                   // only block-wide barrier

    const float2* sloc = (const float2*)sloc4;
    const float2 self = sloc[i];

    // ---- early VMEM reads + independent stores (drain under select) ----
    const size_t E = (size_t)BATCH * NNODE * KSP;
    float* x_out = out;
    float* ei0   = out + (size_t)BATCH * NNODE * DIM;
    float* ei1   = ei0 + E;
    float* eemb  = ei1 + E;

    const int c4 = (lane & 15) << 2;
    const float4 w4 = *(const float4*)(W + c4);
    const float4 b4 = *(const float4*)(bias + c4);

    x_out[(size_t)node * DIM + lane] = emb[(size_t)node * DIM + lane];
    const size_t ebase = (size_t)node * KSP;
    const float fnode = (float)node;
    for (int t = lane; t < KSP; t += 64) ei0[ebase + t] = fnode;

    // ---- pass 1: distances (exact XLA rounding) + histogram (VMEM-free) ----
    for (int j = lane; j < NNODE; j += 64) {
        float2 pt = sloc[j];
        float dx = __fsub_rn(self.x, pt.x);
        float dy = __fsub_rn(self.y, pt.y);
        float d  = __fsqrt_rn(__fadd_rn(__fmul_rn(dx, dx), __fmul_rn(dy, dy)));
        int q = (int)(d * 180.0f);
        q = q > 255 ? 255 : q;
        atomicAdd(&hist[w][q], 1);
    }
    __builtin_amdgcn_wave_barrier();

    // ---- lane-transposed scan: lane l owns bins 4l..4l+3 ----
    int4 h4 = ((int4*)&hist[w][0])[lane];              // ds_read_b128
    int s0 = h4.x;
    int s1 = s0 + h4.y;
    int s2 = s1 + h4.z;
    int s3 = s2 + h4.w;                                // lane total
    int sc = s3;
    #pragma unroll
    for (int off = 1; off < 64; off <<= 1) {
        int y = __shfl_up(sc, off, 64);
        if (lane >= off) sc += y;
    }
    const int excl = sc - s3;                          // exclusive prefix of lane totals
    // smallest bin with inclusive cum >= 201
    int bc = 1 << 30;
    if      (excl + s0 >= KSP + 1) bc = 4 * lane;
    else if (excl + s1 >= KSP + 1) bc = 4 * lane + 1;
    else if (excl + s2 >= KSP + 1) bc = 4 * lane + 2;
    else if (excl + s3 >= KSP + 1) bc = 4 * lane + 3;
    #pragma unroll
    for (int off = 32; off; off >>= 1) bc = min(bc, __shfl_xor(bc, off, 64));
    const int B = bc;
    // write exclusive bin starts back
    int4 st;
    st.x = excl;
    st.y = excl + s0;
    st.z = excl + s1;
    st.w = excl + s2;
    ((int4*)&hist[w][0])[lane] = st;                   // ds_write_b128
    __builtin_amdgcn_wave_barrier();

    // ---- pass 2: counting-sort placement of candidates (q <= B) ----
    for (int j = lane; j < NNODE; j += 64) {
        float2 pt = sloc[j];
        float dx = __fsub_rn(self.x, pt.x);
        float dy = __fsub_rn(self.y, pt.y);
        float d  = __fsqrt_rn(__fadd_rn(__fmul_rn(dx, dx), __fmul_rn(dy, dy)));
        int q = (int)(d * 180.0f);
        q = q > 255 ? 255 : q;
        if (q <= B) {
            int slot = atomicAdd(&hist[w][q], 1);      // old = excl start + prior
            if (slot < 256)
                cand[w][slot] = ((uint64_t)__float_as_uint(d) << 32) | (uint32_t)j;
        }
    }
    __builtin_amdgcn_wave_barrier();
    // hist[q] = inclusive cum (bin end) for q <= B

    const int cumB = min(hist[w][B], 256);

    // ---- exact rank: bin start + count of smaller keys within bin ----
    uint64_t mykey[4];
    int      myrank[4];
    #pragma unroll
    for (int s = 0; s < 4; ++s) {
        int t = lane + s * 64;
        myrank[s] = KSP + 1;
        if (t < cumB) {
            uint64_t k = cand[w][t];
            float d = __uint_as_float((uint32_t)(k >> 32));
            int q = (int)(d * 180.0f);
            q = q > 255 ? 255 : q;
            int start = q ? hist[w][q - 1] : 0;
            int end   = min(hist[w][q], 256);
            int r = start;
            for (int m = start; m < end; ++m)
                r += (cand[w][m] < k) ? 1 : 0;
            mykey[s]  = k;
            myrank[s] = r;
        }
    }
    __builtin_amdgcn_wave_barrier();                   // all reads before permute writes

    // ---- in-place permute (rank <= 200); locate self ----
    #pragma unroll
    for (int s = 0; s < 4; ++s) {
        int t = lane + s * 64;
        if (t < cumB) {
            int r = myrank[s];
            if (r <= KSP) cand[w][r] = mykey[s];
            if ((uint32_t)mykey[s] == (uint32_t)i) ssp[w] = r;   // exactly one lane
        }
    }
    __builtin_amdgcn_wave_barrier();
    const int sp = ssp[w];

    // ---- dependent stores: ei1, eemb ----
    for (int t = lane; t < KSP; t += 64) {
        int slot = t + (t >= sp ? 1 : 0);
        uint64_t kk = cand[w][slot];
        ei1[ebase + t] = (float)(b * NNODE + (int)(uint32_t)kk);
    }

    float4* em4 = (float4*)(eemb + ebase * DIM);
    for (int t = lane; t < KSP * (DIM / 4); t += 64) {
        int e    = t >> 4;
        int slot = e + (e >= sp ? 1 : 0);
        float d = __uint_as_float((uint32_t)(cand[w][slot] >> 32));
        float4 v;
        v.x = fmaf(d, w4.x, b4.x);
        v.y = fmaf(d, w4.y, b4.y);
        v.z = fmaf(d, w4.z, b4.z);
        v.w = fmaf(d, w4.w, b4.w);
        em4[t] = v;
    }
}

extern "C" void kernel_launch(void* const* d_in, const int* in_sizes, int n_in,
                              void* d_out, int out_size, void* d_ws, size_t ws_size,
                              hipStream_t stream) {
    const float* locs = (const float*)d_in[0];
    const float* emb  = (const float*)d_in[1];
    const float* W    = (const float*)d_in[2];
    const float* bias = (const float*)d_in[3];
    float* out = (float*)d_out;

    knn_edge_kernel<<<NBLK, 512, 0, stream>>>(locs, emb, W, bias, out);
}